// Round 3
// baseline (179.147 us; speedup 1.0000x reference)
//
#include <hip/hip_runtime.h>

#define NN 4096
#define BB 512

typedef __attribute__((ext_vector_type(4))) float f32x4;
typedef __attribute__((ext_vector_type(16))) float f32x16;  // 32x32 MFMA C/D
typedef __attribute__((ext_vector_type(4))) int i32x4;
typedef __attribute__((ext_vector_type(8))) int i32x8;      // MFMA A/B frag (32B)
typedef unsigned short ushort;
typedef unsigned char uchar;
typedef unsigned int uint;
typedef __attribute__((ext_vector_type(4))) ushort ushort4v;

#define ASCALE 16384.0f            // 2^14 scale for a -> fp8
#define AINV   6.103515625e-05f    // 2^-14
#define SCL1   0x7f7f7f7f          // e8m0 unit scale (127 -> 2^0) in every byte

__device__ __forceinline__ float scal_val(const void* p) {
    int b = *(const int*)p;
    if (b >= 1 && b <= 1000000) return (float)b;
    return __int_as_float(b);
}

// f32 -> bf16 bits (RNE) and back
__device__ __forceinline__ ushort f2bf(float x) {
    unsigned u = __float_as_uint(x);
    u += 0x7fffu + ((u >> 16) & 1u);
    return (ushort)(u >> 16);
}
__device__ __forceinline__ float bf2f(ushort b) {
    return __uint_as_float((uint)b << 16);
}

// pack 4 floats -> 4 fp8 e4m3 bytes (OCP, RNE+sat via v_cvt_pk_fp8_f32)
__device__ __forceinline__ uint pack4_fp8(float a, float b, float c, float d) {
    int v = __builtin_amdgcn_cvt_pk_fp8_f32(a, b, 0, false);
    v = __builtin_amdgcn_cvt_pk_fp8_f32(c, d, v, true);
    return (uint)v;
}

__device__ __forceinline__ void gload16(const void* g, void* l) {
    __builtin_amdgcn_global_load_lds(
        (const __attribute__((address_space(1))) unsigned int*)g,
        (__attribute__((address_space(3))) unsigned int*)l, 16, 0, 0);
}

__device__ __forceinline__ double wave_sum(double v) {
#pragma unroll
    for (int s = 32; s > 0; s >>= 1) v += __shfl_down(v, s, 64);
    return v;
}

// ---------------------------------------------------------------------------
// Blocked+swizzled global layouts, BK=64 tiles (tile = exact LDS image of one
// K-step; staging = pure linear copy, lane L -> bytes [L*16, L*16+16)).
// Row = 64 B of k (4 units of 16 B); stored unit = logical ^ ((row>>1)&3).
//   A tiles (Kb/KTb): 128 rows x 64 B = 8 KB   (i-block stride 1<<19)
//   B tiles (fT/aT) :  64 rows x 64 B = 4 KB   (j-block stride 1<<18)
// ---------------------------------------------------------------------------
__device__ __forceinline__ int offA(int i, int k) {
    return (((i >> 7) * 64 + (k >> 6)) << 13) + ((i & 127) << 6) +
           ((((k >> 4) & 3) ^ ((i >> 1) & 3)) << 4) + (k & 15);
}
__device__ __forceinline__ int offB(int j, int k) {
    return (((j >> 6) * 64 + (k >> 6)) << 12) + ((j & 63) << 6) +
           ((((k >> 4) & 3) ^ ((j >> 1) & 3)) << 4) + (k & 15);
}

// read one 32-byte MFMA frag (k-bytes [h*32, h*32+32)) from a swizzled LDS
// row.  u0byte = ((h*2) ^ ((r>>1)&3)) * 16 ; the odd unit differs in bit 4.
__device__ __forceinline__ i32x8 frag64(const uchar* rowbase, int u0byte) {
    i32x4 lo = *(const i32x4*)(rowbase + u0byte);
    i32x4 hi = *(const i32x4*)(rowbase + (u0byte ^ 16));
    i32x8 r;
    r[0] = lo[0]; r[1] = lo[1]; r[2] = lo[2]; r[3] = lo[3];
    r[4] = hi[0]; r[5] = hi[1]; r[6] = hi[2]; r[7] = hi[3];
    return r;
}

// Partials (doubles): [0,1024) t1 | [1024,2048) kl | [2048,2560) t2
// | [2560,3072) t3.  Every slot read by k_final is written every call.

// ---------------------------------------------------------------------------
// Merged prep. Blocks [0,4096): K -> Kb + KTb (fp8, blocked+swizzled).
// Blocks [4096,4608): U -> fT (fp8 [j][k], blocked+swizzled).
// ---------------------------------------------------------------------------
__global__ __launch_bounds__(256) void k_prep(const float* __restrict__ K,
                                              const float* __restrict__ U,
                                              uchar* __restrict__ Kb,
                                              uchar* __restrict__ KTb,
                                              uchar* __restrict__ fT,
                                              const void* epsp, const void* lamp) {
    __shared__ float tile[64][65];
    const int t = threadIdx.x;
    const int tx = t & 15, ty = t >> 4;
    const int bid = blockIdx.x;

    if (bid < 4096) {
        const int c0 = (bid & 63) * 64, r0 = (bid >> 6) * 64;
#pragma unroll
        for (int it = 0; it < 4; ++it) {
            int row = ty + it * 16;
            int i = r0 + row;
            float4 v = *(const float4*)&K[(size_t)i * NN + c0 + tx * 4];
            *(uint*)&Kb[offA(i, c0 + tx * 4)] = pack4_fp8(v.x, v.y, v.z, v.w);
            tile[row][tx * 4 + 0] = v.x;
            tile[row][tx * 4 + 1] = v.y;
            tile[row][tx * 4 + 2] = v.z;
            tile[row][tx * 4 + 3] = v.w;
        }
        __syncthreads();
#pragma unroll
        for (int it = 0; it < 4; ++it) {
            int row = ty + it * 16;  // col within tile -> KT row (c0+row)
            int i = c0 + row;        // KT row index
            int k = r0 + tx * 4;     // KT col (reduction) index
            *(uint*)&KTb[offA(i, k)] =
                pack4_fp8(tile[tx * 4 + 0][row], tile[tx * 4 + 1][row],
                          tile[tx * 4 + 2][row], tile[tx * 4 + 3][row]);
        }
    } else {
        const int r = bid - 4096;
        const int c0 = (r & 7) * 64;   // U col tile (j)
        const int r0 = (r >> 3) * 64;  // U row tile (k)
        const float eps = scal_val(epsp), lam = scal_val(lamp);
        const float rr = lam / eps;
#pragma unroll
        for (int it = 0; it < 4; ++it) {
            int row = ty + it * 16;
            float4 v = *(const float4*)&U[(size_t)(r0 + row) * BB + c0 + tx * 4];
            float uu[4] = {v.x, v.y, v.z, v.w};
#pragma unroll
            for (int k = 0; k < 4; ++k) {
                float L = __logf(lam / (lam - uu[k]));
                tile[row][tx * 4 + k] = __expf(rr * L);
            }
        }
        __syncthreads();
#pragma unroll
        for (int it = 0; it < 4; ++it) {
            int row = ty + it * 16;  // j-local row
            int j = c0 + row;
            int k = r0 + tx * 4;
            *(uint*)&fT[offB(j, k)] =
                pack4_fp8(tile[tx * 4 + 0][row], tile[tx * 4 + 1][row],
                          tile[tx * 4 + 2][row], tile[tx * 4 + 3][row]);
        }
    }
}

// ---------------------------------------------------------------------------
// GEMM1 (MX-fp8 32x32x64, unit scales; K-split 8): partial Y1 = Kb@f over a
// K-eighth, stored bf16.  Tile 128(M)x128(j), BK=64, dbuf (32 KB LDS ->
// 4 blocks/CU at grid 1024).  2x2 wave grid: wave (wm,wn) owns 64i x 64j
// -> 4 MFMA per step against 8 KB of LDS frag reads (2 KB/MFMA).
// ---------------------------------------------------------------------------
__global__ __launch_bounds__(256, 4) void k_gemm1(const uchar* __restrict__ Kb,
                                                  const uchar* __restrict__ fT,
                                                  ushort* __restrict__ Y1b) {
    __shared__ __align__(16) uchar As[2][128 * 64];   // 8 KB x2
    __shared__ __align__(16) uchar Bs[2][128 * 64];   // 8 KB x2

    const int tid = threadIdx.x;
    const int lane = tid & 63;
    const int w = tid >> 6;
    const int wm = w >> 1, wn = w & 1;
    const int bid = blockIdx.x;
    const int kh = bid & 7;                  // K-eighth
    const int i0 = ((bid >> 3) & 31) * 128;  // M panel
    const int j0 = (bid >> 8) * 128;         // j panel (4 panels)
    const int h = lane >> 5;                 // k-half of frag
    const int r = lane & 31;                 // row/col within 32
    const int u0b = (((h << 1) ^ ((r >> 1) & 3)) << 4);

    f32x16 acc[2][2];
#pragma unroll
    for (int mt = 0; mt < 2; ++mt)
#pragma unroll
        for (int nt = 0; nt < 2; ++nt) acc[mt][nt] = (f32x16)(0.0f);

    const uchar* apanel = Kb + ((size_t)(i0 >> 7) << 19);
    const uchar* bpanel = fT + ((size_t)(j0 >> 6) << 18);

    auto stage = [&](int ks, int b) {
        const uchar* ga = apanel + ((size_t)ks << 13) + w * 2048 + lane * 16;
        gload16(ga, &As[b][w * 2048]);
        gload16(ga + 1024, &As[b][w * 2048 + 1024]);
        // B rows [0,64) = j-block 0, rows [64,128) = j-block 1 (stride 1<<18)
        const uchar* gb = bpanel + (((size_t)(w >> 1)) << 18) +
                          ((size_t)ks << 12) + (w & 1) * 2048 + lane * 16;
        gload16(gb, &Bs[b][w * 2048]);
        gload16(gb + 1024, &Bs[b][w * 2048 + 1024]);
    };

    const int ks0 = kh * 8;
    stage(ks0, 0);
    __syncthreads();
    for (int step = 0; step < 8; ++step) {   // 8 steps of BK=64
        const int cur = step & 1;
        if (step < 7) stage(ks0 + step + 1, cur ^ 1);
        i32x8 av[2], bv[2];
#pragma unroll
        for (int mt = 0; mt < 2; ++mt)
            av[mt] = frag64(&As[cur][(wm * 64 + mt * 32 + r) << 6], u0b);
#pragma unroll
        for (int nt = 0; nt < 2; ++nt)
            bv[nt] = frag64(&Bs[cur][(wn * 64 + nt * 32 + r) << 6], u0b);
#pragma unroll
        for (int mt = 0; mt < 2; ++mt)
#pragma unroll
            for (int nt = 0; nt < 2; ++nt)
                acc[mt][nt] = __builtin_amdgcn_mfma_scale_f32_32x32x64_f8f6f4(
                    av[mt], bv[nt], acc[mt][nt], 0, 0, 0, SCL1, 0, SCL1);
        __syncthreads();
    }

    // Store bf16 partial [kh][i][j].  C/D: col=lane&31,
    // row = (reg&3) + 8*(reg>>2) + 4*(lane>>5).
    ushort* o1 = Y1b + (size_t)kh * NN * BB;
#pragma unroll
    for (int mt = 0; mt < 2; ++mt)
#pragma unroll
        for (int nt = 0; nt < 2; ++nt) {
            const int jb = j0 + wn * 64 + nt * 32 + r;
#pragma unroll
            for (int reg = 0; reg < 16; ++reg) {
                const int row =
                    i0 + wm * 64 + mt * 32 + (reg & 3) + 8 * (reg >> 2) + 4 * h;
                o1[(size_t)row * BB + jb] = f2bf(acc[mt][nt][reg]);
            }
        }
}

// ---------------------------------------------------------------------------
// Epilogue: Y1 = sum of 8 bf16 eighths; a = P/Y1; t2 += P*log(a), t3 += P;
// aT (fp8 * 2^14, blocked+swizzled) via LDS transpose.  No atomics.
// ---------------------------------------------------------------------------
__global__ __launch_bounds__(256) void k_epi(const ushort* __restrict__ Y1b,
                                             const float* __restrict__ P,
                                             uchar* __restrict__ aT,
                                             double* __restrict__ parts) {
    __shared__ float ta[64][65];
    __shared__ double bred[4][2];
    const int t = threadIdx.x;
    const int lane = t & 63;
    const int w = t >> 6;
    const int tx = t & 15, ty = t >> 4;
    const int j0 = blockIdx.x * 64;
    const int i0 = blockIdx.y * 64;
    const int bid = blockIdx.y * 8 + blockIdx.x;
    const size_t H = (size_t)NN * BB;

    double t2 = 0.0, t3 = 0.0;
#pragma unroll
    for (int it = 0; it < 4; ++it) {
        int row = ty + it * 16;
        size_t off = (size_t)(i0 + row) * BB + j0 + tx * 4;
        float y1[4] = {0.f, 0.f, 0.f, 0.f};
#pragma unroll
        for (int pl = 0; pl < 8; ++pl) {
            ushort4v qq = *(const ushort4v*)(Y1b + (size_t)pl * H + off);
#pragma unroll
            for (int e = 0; e < 4; ++e) y1[e] += bf2f(qq[e]);
        }
        float4 p4 = *(const float4*)(P + off);
        float pv[4] = {p4.x, p4.y, p4.z, p4.w};
#pragma unroll
        for (int e = 0; e < 4; ++e) {
            float aij = pv[e] / y1[e];
            t2 += (double)(pv[e] * __logf(aij));
            t3 += (double)pv[e];
            ta[row][tx * 4 + e] = aij * ASCALE;
        }
    }
    __syncthreads();
#pragma unroll
    for (int it = 0; it < 4; ++it) {
        int row = ty + it * 16;  // col within tile -> aT row (j0+row), k=i0+tx*4
        int j = j0 + row;
        *(uint*)&aT[offB(j, i0 + tx * 4)] =
            pack4_fp8(ta[tx * 4 + 0][row], ta[tx * 4 + 1][row],
                      ta[tx * 4 + 2][row], ta[tx * 4 + 3][row]);
    }

    t2 = wave_sum(t2); t3 = wave_sum(t3);
    if (lane == 0) { bred[w][0] = t2; bred[w][1] = t3; }
    __syncthreads();
    if (t == 0) {
        double b = 0, c = 0;
#pragma unroll
        for (int ww = 0; ww < 4; ++ww) { b += bred[ww][0]; c += bred[ww][1]; }
        parts[2048 + bid] = b;
        parts[2560 + bid] = c;
    }
}

// ---------------------------------------------------------------------------
// GEMM2 (MX-fp8 32x32x64, unit scales; K-split 8): partial S' = KTb @ a'
// (a scaled 2^14).  Epilogue (linear in S): t1 += g*S, kl -= f*(1+L)*S.
// Same 128x128 / 2x2-wave structure as k_gemm1.
// ---------------------------------------------------------------------------
__global__ __launch_bounds__(256, 4) void k_gemm2(const uchar* __restrict__ KTb,
                                                  const uchar* __restrict__ aT,
                                                  const float* __restrict__ U,
                                                  const void* epsp, const void* lamp,
                                                  double* __restrict__ parts) {
    __shared__ __align__(16) uchar As[2][128 * 64];
    __shared__ __align__(16) uchar Bs[2][128 * 64];
    __shared__ double bred[4][2];

    const float eps = scal_val(epsp), lam = scal_val(lamp);
    const float rr = lam / eps;
    const int tid = threadIdx.x;
    const int lane = tid & 63;
    const int w = tid >> 6;
    const int wm = w >> 1, wn = w & 1;
    const int bid = blockIdx.x;
    const int kh = bid & 7;
    const int i0 = ((bid >> 3) & 31) * 128;
    const int j0 = (bid >> 8) * 128;
    const int h = lane >> 5;
    const int r = lane & 31;
    const int u0b = (((h << 1) ^ ((r >> 1) & 3)) << 4);

    f32x16 acc[2][2];
#pragma unroll
    for (int mt = 0; mt < 2; ++mt)
#pragma unroll
        for (int nt = 0; nt < 2; ++nt) acc[mt][nt] = (f32x16)(0.0f);

    const uchar* apanel = KTb + ((size_t)(i0 >> 7) << 19);
    const uchar* bpanel = aT + ((size_t)(j0 >> 6) << 18);

    auto stage = [&](int ks, int b) {
        const uchar* ga = apanel + ((size_t)ks << 13) + w * 2048 + lane * 16;
        gload16(ga, &As[b][w * 2048]);
        gload16(ga + 1024, &As[b][w * 2048 + 1024]);
        const uchar* gb = bpanel + (((size_t)(w >> 1)) << 18) +
                          ((size_t)ks << 12) + (w & 1) * 2048 + lane * 16;
        gload16(gb, &Bs[b][w * 2048]);
        gload16(gb + 1024, &Bs[b][w * 2048 + 1024]);
    };

    const int ks0 = kh * 8;
    stage(ks0, 0);
    __syncthreads();
    for (int step = 0; step < 8; ++step) {
        const int cur = step & 1;
        if (step < 7) stage(ks0 + step + 1, cur ^ 1);
        i32x8 av[2], bv[2];
#pragma unroll
        for (int mt = 0; mt < 2; ++mt)
            av[mt] = frag64(&As[cur][(wm * 64 + mt * 32 + r) << 6], u0b);
#pragma unroll
        for (int nt = 0; nt < 2; ++nt)
            bv[nt] = frag64(&Bs[cur][(wn * 64 + nt * 32 + r) << 6], u0b);
#pragma unroll
        for (int mt = 0; mt < 2; ++mt)
#pragma unroll
            for (int nt = 0; nt < 2; ++nt)
                acc[mt][nt] = __builtin_amdgcn_mfma_scale_f32_32x32x64_f8f6f4(
                    av[mt], bv[nt], acc[mt][nt], 0, 0, 0, SCL1, 0, SCL1);
        __syncthreads();
    }

    double t1p = 0.0, klp = 0.0;
#pragma unroll
    for (int mt = 0; mt < 2; ++mt)
#pragma unroll
        for (int nt = 0; nt < 2; ++nt) {
            const int jb = j0 + wn * 64 + nt * 32 + r;
#pragma unroll
            for (int reg = 0; reg < 16; ++reg) {
                const int ib =
                    i0 + wm * 64 + mt * 32 + (reg & 3) + 8 * (reg >> 2) + 4 * h;
                float s = acc[mt][nt][reg] * AINV;
                float u = U[(size_t)ib * BB + jb];
                float L = __logf(lam / (lam - u));
                float fv = __expf(rr * L);
                t1p += (double)(fv * rr * L * s);       // g*S
                klp -= (double)(fv * (1.0f + L) * s);   // -f*(1+L)*S
            }
        }

    t1p = wave_sum(t1p); klp = wave_sum(klp);
    if (lane == 0) { bred[w][0] = t1p; bred[w][1] = klp; }
    __syncthreads();
    if (tid == 0) {
        double a = 0, b = 0;
#pragma unroll
        for (int ww = 0; ww < 4; ++ww) { a += bred[ww][0]; b += bred[ww][1]; }
        parts[bid] = a;
        parts[1024 + bid] = b;
    }
}

// ---------------------------------------------------------------------------
// Final: sum partials, out = eps*(t1+t2-t3) + lam*kl
// ---------------------------------------------------------------------------
__global__ __launch_bounds__(256) void k_final(const double* __restrict__ parts,
                                               const void* epsp, const void* lamp,
                                               float* __restrict__ out) {
    __shared__ double red[4][4];
    const int tid = threadIdx.x;
    const int lane = tid & 63, w = tid >> 6;
    double s0 = 0.0, s1 = 0.0, s2 = 0.0, s3 = 0.0;
    for (int i = tid; i < 1024; i += 256) {
        s0 += parts[i];          // t1
        s1 += parts[1024 + i];   // kl
    }
    for (int i = tid; i < 512; i += 256) {
        s2 += parts[2048 + i];   // t2
        s3 += parts[2560 + i];   // t3
    }
    s0 = wave_sum(s0); s1 = wave_sum(s1); s2 = wave_sum(s2); s3 = wave_sum(s3);
    if (lane == 0) { red[w][0] = s0; red[w][1] = s1; red[w][2] = s2; red[w][3] = s3; }
    __syncthreads();
    if (tid == 0) {
        double t1 = 0, kl = 0, t2 = 0, t3 = 0;
#pragma unroll
        for (int ww = 0; ww < 4; ++ww) {
            t1 += red[ww][0]; kl += red[ww][1]; t2 += red[ww][2]; t3 += red[ww][3];
        }
        float eps = scal_val(epsp), lam = scal_val(lamp);
        out[0] = (float)((double)eps * (t1 + t2 - t3) + (double)lam * kl);
    }
}

extern "C" void kernel_launch(void* const* d_in, const int* in_sizes, int n_in,
                              void* d_out, int out_size, void* d_ws, size_t ws_size,
                              hipStream_t stream) {
    const float* U = (const float*)d_in[0];
    const float* P = (const float*)d_in[1];
    const float* K = (const float*)d_in[2];
    const void* epsp = d_in[3];
    const void* lamp = d_in[4];

    // ws: parts 24KB (pad 64KB) | Kb 16M | KTb 16M | fT 2M | aT 2M | Y1b 32M
    double* parts = (double*)d_ws;
    char* base = (char*)d_ws + (64 << 10);
    uchar* Kb   = (uchar*)base;
    uchar* KTb  = (uchar*)(base + ((size_t)16 << 20));
    uchar* fT   = (uchar*)(base + ((size_t)32 << 20));
    uchar* aT   = (uchar*)(base + ((size_t)34 << 20));
    ushort* Y1b = (ushort*)(base + ((size_t)36 << 20));

    k_prep<<<4608, 256, 0, stream>>>(K, U, Kb, KTb, fT, epsp, lamp);
    k_gemm1<<<1024, 256, 0, stream>>>(Kb, fT, Y1b);
    k_epi<<<dim3(8, 64), 256, 0, stream>>>(Y1b, P, aT, parts);
    k_gemm2<<<1024, 256, 0, stream>>>(KTb, aT, U, epsp, lamp, parts);
    k_final<<<1, 256, 0, stream>>>(parts, epsp, lamp, (float*)d_out);
}

// Round 5
// 155.659 us; speedup vs baseline: 1.1509x; 1.1509x over previous
//
#include <hip/hip_runtime.h>

#define NN 4096
#define BB 512

typedef __attribute__((ext_vector_type(4))) float f32x4;
typedef __attribute__((ext_vector_type(16))) float f32x16;  // 32x32 MFMA C/D
typedef __attribute__((ext_vector_type(4))) int i32x4;
typedef __attribute__((ext_vector_type(8))) int i32x8;      // MFMA A/B frag (32B)
typedef unsigned short ushort;
typedef unsigned char uchar;
typedef unsigned int uint;
typedef __attribute__((ext_vector_type(4))) ushort ushort4v;

#define ASCALE 16384.0f            // 2^14 scale for a -> fp8
#define AINV   6.103515625e-05f    // 2^-14
#define SCL1   0x7f7f7f7f          // e8m0 unit scale (127 -> 2^0) in every byte

__device__ __forceinline__ float scal_val(const void* p) {
    int b = *(const int*)p;
    if (b >= 1 && b <= 1000000) return (float)b;
    return __int_as_float(b);
}

// f32 -> bf16 bits (RNE) and back
__device__ __forceinline__ ushort f2bf(float x) {
    unsigned u = __float_as_uint(x);
    u += 0x7fffu + ((u >> 16) & 1u);
    return (ushort)(u >> 16);
}
__device__ __forceinline__ float bf2f(ushort b) {
    return __uint_as_float((uint)b << 16);
}

// pack 4 floats -> 4 fp8 e4m3 bytes (OCP, RNE+sat via v_cvt_pk_fp8_f32)
__device__ __forceinline__ uint pack4_fp8(float a, float b, float c, float d) {
    int v = __builtin_amdgcn_cvt_pk_fp8_f32(a, b, 0, false);
    v = __builtin_amdgcn_cvt_pk_fp8_f32(c, d, v, true);
    return (uint)v;
}

__device__ __forceinline__ void gload16(const void* g, void* l) {
    __builtin_amdgcn_global_load_lds(
        (const __attribute__((address_space(1))) unsigned int*)g,
        (__attribute__((address_space(3))) unsigned int*)l, 16, 0, 0);
}

__device__ __forceinline__ double wave_sum(double v) {
#pragma unroll
    for (int s = 32; s > 0; s >>= 1) v += __shfl_down(v, s, 64);
    return v;
}

// ---------------------------------------------------------------------------
// Blocked+swizzled global layouts, BK=64 tiles (tile = exact LDS image of one
// K-step; staging = pure linear copy, lane L -> bytes [L*16, L*16+16)).
// Row = 64 B of k (4 units of 16 B); stored unit = logical ^ ((row>>1)&3).
//   A tiles (Kb/KTb): 128 rows x 64 B = 8 KB   (i-block stride 1<<19)
//   B tiles (fT/aT) :  64 rows x 64 B = 4 KB   (j-block stride 1<<18)
// ---------------------------------------------------------------------------
__device__ __forceinline__ int offA(int i, int k) {
    return (((i >> 7) * 64 + (k >> 6)) << 13) + ((i & 127) << 6) +
           ((((k >> 4) & 3) ^ ((i >> 1) & 3)) << 4) + (k & 15);
}
__device__ __forceinline__ int offB(int j, int k) {
    return (((j >> 6) * 64 + (k >> 6)) << 12) + ((j & 63) << 6) +
           ((((k >> 4) & 3) ^ ((j >> 1) & 3)) << 4) + (k & 15);
}

// read one 32-byte MFMA frag (k-bytes [h*32, h*32+32)) from a swizzled LDS
// row.  u0byte = ((h*2) ^ ((r>>1)&3)) * 16 ; the odd unit differs in bit 4.
__device__ __forceinline__ i32x8 frag64(const uchar* rowbase, int u0byte) {
    i32x4 lo = *(const i32x4*)(rowbase + u0byte);
    i32x4 hi = *(const i32x4*)(rowbase + (u0byte ^ 16));
    i32x8 r;
    r[0] = lo[0]; r[1] = lo[1]; r[2] = lo[2]; r[3] = lo[3];
    r[4] = hi[0]; r[5] = hi[1]; r[6] = hi[2]; r[7] = hi[3];
    return r;
}

// Partials (doubles): [0,1024) t1 | [1024,2048) kl | [2048,2560) t2
// | [2560,3072) t3.  Every slot read by k_final is written every call.

// ---------------------------------------------------------------------------
// Merged prep. Blocks [0,4096): K -> Kb + KTb (fp8, blocked+swizzled).
// Blocks [4096,4608): U -> fT (fp8 [j][k], blocked+swizzled).
// ---------------------------------------------------------------------------
__global__ __launch_bounds__(256) void k_prep(const float* __restrict__ K,
                                              const float* __restrict__ U,
                                              uchar* __restrict__ Kb,
                                              uchar* __restrict__ KTb,
                                              uchar* __restrict__ fT,
                                              const void* epsp, const void* lamp) {
    __shared__ float tile[64][65];
    const int t = threadIdx.x;
    const int tx = t & 15, ty = t >> 4;
    const int bid = blockIdx.x;

    if (bid < 4096) {
        const int c0 = (bid & 63) * 64, r0 = (bid >> 6) * 64;
#pragma unroll
        for (int it = 0; it < 4; ++it) {
            int row = ty + it * 16;
            int i = r0 + row;
            float4 v = *(const float4*)&K[(size_t)i * NN + c0 + tx * 4];
            *(uint*)&Kb[offA(i, c0 + tx * 4)] = pack4_fp8(v.x, v.y, v.z, v.w);
            tile[row][tx * 4 + 0] = v.x;
            tile[row][tx * 4 + 1] = v.y;
            tile[row][tx * 4 + 2] = v.z;
            tile[row][tx * 4 + 3] = v.w;
        }
        __syncthreads();
#pragma unroll
        for (int it = 0; it < 4; ++it) {
            int row = ty + it * 16;  // col within tile -> KT row (c0+row)
            int i = c0 + row;        // KT row index
            int k = r0 + tx * 4;     // KT col (reduction) index
            *(uint*)&KTb[offA(i, k)] =
                pack4_fp8(tile[tx * 4 + 0][row], tile[tx * 4 + 1][row],
                          tile[tx * 4 + 2][row], tile[tx * 4 + 3][row]);
        }
    } else {
        const int r = bid - 4096;
        const int c0 = (r & 7) * 64;   // U col tile (j)
        const int r0 = (r >> 3) * 64;  // U row tile (k)
        const float eps = scal_val(epsp), lam = scal_val(lamp);
        const float rr = lam / eps;
#pragma unroll
        for (int it = 0; it < 4; ++it) {
            int row = ty + it * 16;
            float4 v = *(const float4*)&U[(size_t)(r0 + row) * BB + c0 + tx * 4];
            float uu[4] = {v.x, v.y, v.z, v.w};
#pragma unroll
            for (int k = 0; k < 4; ++k) {
                float L = __logf(lam / (lam - uu[k]));
                tile[row][tx * 4 + k] = __expf(rr * L);
            }
        }
        __syncthreads();
#pragma unroll
        for (int it = 0; it < 4; ++it) {
            int row = ty + it * 16;  // j-local row
            int j = c0 + row;
            int k = r0 + tx * 4;
            *(uint*)&fT[offB(j, k)] =
                pack4_fp8(tile[tx * 4 + 0][row], tile[tx * 4 + 1][row],
                          tile[tx * 4 + 2][row], tile[tx * 4 + 3][row]);
        }
    }
}

// ---------------------------------------------------------------------------
// GEMM1 (MX-fp8 32x32x64, unit scales; K-split 4): partial Y1 = Kb@f over a
// K-quarter, stored bf16.  Tile 128(M)x64(j), BK=64.  3-buffer / 2-tile-ahead
// prefetch with counted vmcnt (never 0 in the loop) + raw s_barrier +
// sched_barrier(0) fences.  36 KB LDS; no launch_bounds min-wave clamp
// (avoid forced spills -> scratch VMEM would corrupt vmcnt counting).
// ---------------------------------------------------------------------------
__global__ __launch_bounds__(256) void k_gemm1(const uchar* __restrict__ Kb,
                                               const uchar* __restrict__ fT,
                                               ushort* __restrict__ Y1b) {
    __shared__ __align__(16) uchar As[3][128 * 64];   // 8 KB x3
    __shared__ __align__(16) uchar Bf[3][64 * 64];    // 4 KB x3

    const int tid = threadIdx.x;
    const int lane = tid & 63;
    const int w = tid >> 6;
    const int bid = blockIdx.x;
    const int kh = bid & 3;                  // K-quarter
    const int i0 = ((bid >> 2) & 31) * 128;  // M panel
    const int j0 = (bid >> 7) * 64;          // j panel
    const int h = lane >> 5;                 // k-half of frag
    const int r = lane & 31;                 // row/col within 32
    const int u0b = (((h << 1) ^ ((r >> 1) & 3)) << 4);

    f32x16 acc0 = {}, acc1 = {};

    const uchar* apanel = Kb + ((size_t)(i0 >> 7) << 19);  // *64*8192
    const uchar* bpanel = fT + ((size_t)(j0 >> 6) << 18);  // *64*4096

    auto stage = [&](int ks, int b) {    // 3 VMEM ops per wave
        const uchar* ga = apanel + ((size_t)ks << 13) + w * 2048 + lane * 16;
        gload16(ga, &As[b][w * 2048]);
        gload16(ga + 1024, &As[b][w * 2048 + 1024]);
        const uchar* gb = bpanel + ((size_t)ks << 12) + w * 1024 + lane * 16;
        gload16(gb, &Bf[b][w * 1024]);
    };

    const int ks0 = kh * 16;
    stage(ks0, 0);
    stage(ks0 + 1, 1);
    int cur = 0, pf = 2;
    for (int step = 0; step < 16; ++step) {   // 16 steps of BK=64
        // wait for tile `step` (own 3 loads are the 3 oldest outstanding);
        // tile step+1's 3 loads stay in flight across the barrier.
        if (step < 15) asm volatile("s_waitcnt vmcnt(3)" ::: "memory");
        else           asm volatile("s_waitcnt vmcnt(0)" ::: "memory");
        __builtin_amdgcn_s_barrier();        // all waves: tile `step` in LDS
        __builtin_amdgcn_sched_barrier(0);   // nothing moves above this point
        if (step < 14) stage(ks0 + step + 2, pf);  // target = buf of step-1,
        // whose reads retired before the barrier above (read in step-1).
        i32x8 av = frag64(&As[cur][(w * 32 + r) << 6], u0b);
        i32x8 bv0 = frag64(&Bf[cur][r << 6], u0b);
        i32x8 bv1 = frag64(&Bf[cur][(32 + r) << 6], u0b);
        acc0 = __builtin_amdgcn_mfma_scale_f32_32x32x64_f8f6f4(
            av, bv0, acc0, 0, 0, 0, SCL1, 0, SCL1);
        acc1 = __builtin_amdgcn_mfma_scale_f32_32x32x64_f8f6f4(
            av, bv1, acc1, 0, 0, 0, SCL1, 0, SCL1);
        __builtin_amdgcn_sched_barrier(0);   // no motion across iterations
        cur = (cur == 2) ? 0 : cur + 1;
        pf = (pf == 2) ? 0 : pf + 1;
    }

    // Store bf16 partial [kh][i][j].  C/D: col=lane&31,
    // row = (reg&3) + 8*(reg>>2) + 4*(lane>>5).
    ushort* o1 = Y1b + (size_t)kh * NN * BB;
#pragma unroll
    for (int reg = 0; reg < 16; ++reg) {
        const int row = i0 + w * 32 + (reg & 3) + 8 * (reg >> 2) + 4 * h;
        o1[(size_t)row * BB + j0 + r] = f2bf(acc0[reg]);
        o1[(size_t)row * BB + j0 + 32 + r] = f2bf(acc1[reg]);
    }
}

// ---------------------------------------------------------------------------
// Epilogue: Y1 = sum of 4 bf16 quarters; a = P/Y1; t2 += P*log(a), t3 += P;
// aT (fp8 * 2^14, blocked+swizzled) via LDS transpose.  No atomics.
// ---------------------------------------------------------------------------
__global__ __launch_bounds__(256) void k_epi(const ushort* __restrict__ Y1b,
                                             const float* __restrict__ P,
                                             uchar* __restrict__ aT,
                                             double* __restrict__ parts) {
    __shared__ float ta[64][65];
    __shared__ double bred[4][2];
    const int t = threadIdx.x;
    const int lane = t & 63;
    const int w = t >> 6;
    const int tx = t & 15, ty = t >> 4;
    const int j0 = blockIdx.x * 64;
    const int i0 = blockIdx.y * 64;
    const int bid = blockIdx.y * 8 + blockIdx.x;
    const size_t H = (size_t)NN * BB;

    double t2 = 0.0, t3 = 0.0;
#pragma unroll
    for (int it = 0; it < 4; ++it) {
        int row = ty + it * 16;
        size_t off = (size_t)(i0 + row) * BB + j0 + tx * 4;
        ushort4v q0 = *(const ushort4v*)(Y1b + off);
        ushort4v q1 = *(const ushort4v*)(Y1b + H + off);
        ushort4v q2 = *(const ushort4v*)(Y1b + 2 * H + off);
        ushort4v q3 = *(const ushort4v*)(Y1b + 3 * H + off);
        float4 p4 = *(const float4*)(P + off);
        float pv[4] = {p4.x, p4.y, p4.z, p4.w};
#pragma unroll
        for (int e = 0; e < 4; ++e) {
            float y1 = bf2f(q0[e]) + bf2f(q1[e]) + bf2f(q2[e]) + bf2f(q3[e]);
            float aij = pv[e] / y1;
            t2 += (double)(pv[e] * __logf(aij));
            t3 += (double)pv[e];
            ta[row][tx * 4 + e] = aij * ASCALE;
        }
    }
    __syncthreads();
#pragma unroll
    for (int it = 0; it < 4; ++it) {
        int row = ty + it * 16;  // col within tile -> aT row (j0+row), k=i0+tx*4
        int j = j0 + row;
        *(uint*)&aT[offB(j, i0 + tx * 4)] =
            pack4_fp8(ta[tx * 4 + 0][row], ta[tx * 4 + 1][row],
                      ta[tx * 4 + 2][row], ta[tx * 4 + 3][row]);
    }

    t2 = wave_sum(t2); t3 = wave_sum(t3);
    if (lane == 0) { bred[w][0] = t2; bred[w][1] = t3; }
    __syncthreads();
    if (t == 0) {
        double b = 0, c = 0;
#pragma unroll
        for (int ww = 0; ww < 4; ++ww) { b += bred[ww][0]; c += bred[ww][1]; }
        parts[2048 + bid] = b;
        parts[2560 + bid] = c;
    }
}

// ---------------------------------------------------------------------------
// GEMM2 (MX-fp8 32x32x64, unit scales; K-split 4): partial S' = KTb @ a'
// (a scaled 2^14).  Same 3-buffer counted-vmcnt pipeline as k_gemm1.
// Epilogue (linear in S): t1 += g*S, kl -= f*(1+L)*S.
// ---------------------------------------------------------------------------
__global__ __launch_bounds__(256) void k_gemm2(const uchar* __restrict__ KTb,
                                               const uchar* __restrict__ aT,
                                               const float* __restrict__ U,
                                               const void* epsp, const void* lamp,
                                               double* __restrict__ parts) {
    __shared__ __align__(16) uchar As[3][128 * 64];
    __shared__ __align__(16) uchar Bs[3][64 * 64];
    __shared__ double bred[4][2];

    const float eps = scal_val(epsp), lam = scal_val(lamp);
    const float rr = lam / eps;
    const int tid = threadIdx.x;
    const int lane = tid & 63;
    const int w = tid >> 6;
    const int bid = blockIdx.x;
    const int kh = bid & 3;
    const int i0 = ((bid >> 2) & 31) * 128;
    const int j0 = (bid >> 7) * 64;
    const int h = lane >> 5;
    const int r = lane & 31;
    const int u0b = (((h << 1) ^ ((r >> 1) & 3)) << 4);

    f32x16 acc0 = {}, acc1 = {};

    const uchar* apanel = KTb + ((size_t)(i0 >> 7) << 19);
    const uchar* bpanel = aT + ((size_t)(j0 >> 6) << 18);

    auto stage = [&](int ks, int b) {    // 3 VMEM ops per wave
        const uchar* ga = apanel + ((size_t)ks << 13) + w * 2048 + lane * 16;
        gload16(ga, &As[b][w * 2048]);
        gload16(ga + 1024, &As[b][w * 2048 + 1024]);
        const uchar* gb = bpanel + ((size_t)ks << 12) + w * 1024 + lane * 16;
        gload16(gb, &Bs[b][w * 1024]);
    };

    const int ks0 = kh * 16;
    stage(ks0, 0);
    stage(ks0 + 1, 1);
    int cur = 0, pf = 2;
    for (int step = 0; step < 16; ++step) {
        if (step < 15) asm volatile("s_waitcnt vmcnt(3)" ::: "memory");
        else           asm volatile("s_waitcnt vmcnt(0)" ::: "memory");
        __builtin_amdgcn_s_barrier();
        __builtin_amdgcn_sched_barrier(0);
        if (step < 14) stage(ks0 + step + 2, pf);
        i32x8 av = frag64(&As[cur][(w * 32 + r) << 6], u0b);
        i32x8 bv0 = frag64(&Bs[cur][r << 6], u0b);
        i32x8 bv1 = frag64(&Bs[cur][(32 + r) << 6], u0b);
        acc0 = __builtin_amdgcn_mfma_scale_f32_32x32x64_f8f6f4(
            av, bv0, acc0, 0, 0, 0, SCL1, 0, SCL1);
        acc1 = __builtin_amdgcn_mfma_scale_f32_32x32x64_f8f6f4(
            av, bv1, acc1, 0, 0, 0, SCL1, 0, SCL1);
        __builtin_amdgcn_sched_barrier(0);
        cur = (cur == 2) ? 0 : cur + 1;
        pf = (pf == 2) ? 0 : pf + 1;
    }

    double t1p = 0.0, klp = 0.0;
#pragma unroll
    for (int reg = 0; reg < 16; ++reg) {
        const int ib = i0 + w * 32 + (reg & 3) + 8 * (reg >> 2) + 4 * h;  // k idx
#pragma unroll
        for (int nt = 0; nt < 2; ++nt) {
            const int j = j0 + nt * 32 + r;
            float s = (nt ? acc1[reg] : acc0[reg]) * AINV;
            float u = U[(size_t)ib * BB + j];
            float L = __logf(lam / (lam - u));
            float fv = __expf(rr * L);
            t1p += (double)(fv * rr * L * s);       // g*S
            klp -= (double)(fv * (1.0f + L) * s);   // -f*(1+L)*S
        }
    }

    t1p = wave_sum(t1p); klp = wave_sum(klp);
    if (lane == 0) { bred[w][0] = t1p; bred[w][1] = klp; }
    __syncthreads();
    if (tid == 0) {
        double a = 0, b = 0;
#pragma unroll
        for (int ww = 0; ww < 4; ++ww) { a += bred[ww][0]; b += bred[ww][1]; }
        parts[bid] = a;
        parts[1024 + bid] = b;
    }
}

// ---------------------------------------------------------------------------
// Final: sum partials, out = eps*(t1+t2-t3) + lam*kl
// ---------------------------------------------------------------------------
__global__ __launch_bounds__(256) void k_final(const double* __restrict__ parts,
                                               const void* epsp, const void* lamp,
                                               float* __restrict__ out) {
    __shared__ double red[4][4];
    const int tid = threadIdx.x;
    const int lane = tid & 63, w = tid >> 6;
    double s0 = 0.0, s1 = 0.0, s2 = 0.0, s3 = 0.0;
    for (int i = tid; i < 1024; i += 256) {
        s0 += parts[i];          // t1
        s1 += parts[1024 + i];   // kl
    }
    for (int i = tid; i < 512; i += 256) {
        s2 += parts[2048 + i];   // t2
        s3 += parts[2560 + i];   // t3
    }
    s0 = wave_sum(s0); s1 = wave_sum(s1); s2 = wave_sum(s2); s3 = wave_sum(s3);
    if (lane == 0) { red[w][0] = s0; red[w][1] = s1; red[w][2] = s2; red[w][3] = s3; }
    __syncthreads();
    if (tid == 0) {
        double t1 = 0, kl = 0, t2 = 0, t3 = 0;
#pragma unroll
        for (int ww = 0; ww < 4; ++ww) {
            t1 += red[ww][0]; kl += red[ww][1]; t2 += red[ww][2]; t3 += red[ww][3];
        }
        float eps = scal_val(epsp), lam = scal_val(lamp);
        out[0] = (float)((double)eps * (t1 + t2 - t3) + (double)lam * kl);
    }
}

extern "C" void kernel_launch(void* const* d_in, const int* in_sizes, int n_in,
                              void* d_out, int out_size, void* d_ws, size_t ws_size,
                              hipStream_t stream) {
    const float* U = (const float*)d_in[0];
    const float* P = (const float*)d_in[1];
    const float* K = (const float*)d_in[2];
    const void* epsp = d_in[3];
    const void* lamp = d_in[4];

    // ws: parts 24KB (pad 64KB) | Kb 16M | KTb 16M | fT 2M | aT 2M | Y1b 16M
    double* parts = (double*)d_ws;
    char* base = (char*)d_ws + (64 << 10);
    uchar* Kb   = (uchar*)base;
    uchar* KTb  = (uchar*)(base + ((size_t)16 << 20));
    uchar* fT   = (uchar*)(base + ((size_t)32 << 20));
    uchar* aT   = (uchar*)(base + ((size_t)34 << 20));
    ushort* Y1b = (ushort*)(base + ((size_t)36 << 20));

    k_prep<<<4608, 256, 0, stream>>>(K, U, Kb, KTb, fT, epsp, lamp);
    k_gemm1<<<1024, 256, 0, stream>>>(Kb, fT, Y1b);
    k_epi<<<dim3(8, 64), 256, 0, stream>>>(Y1b, P, aT, parts);
    k_gemm2<<<1024, 256, 0, stream>>>(KTb, aT, U, epsp, lamp, parts);
    k_final<<<1, 256, 0, stream>>>(parts, epsp, lamp, (float*)d_out);
}